// Round 1
// baseline (2717.591 us; speedup 1.0000x reference)
//
#include <hip/hip_runtime.h>
#include <math.h>

#define DD 128

static inline int cdiv(long a, long b){ return (int)((a + b - 1) / b); }

__global__ void k_init_ones(float* __restrict__ p, int n){
  int i = blockIdx.x * blockDim.x + threadIdx.x;
  if (i < n) p[i] = 1.0f;
}

__global__ void k_deg(const int* __restrict__ dst, float* __restrict__ deg, int E){
  int e = blockIdx.x * blockDim.x + threadIdx.x;
  if (e < E) atomicAdd(&deg[dst[e]], 1.0f);
}

__global__ void k_rsqrt(float* __restrict__ p, int n){
  int i = blockIdx.x * blockDim.x + threadIdx.x;
  if (i < n) p[i] = rsqrtf(p[i]);
}

// C[n,128] = A[n,128] @ W[128,128]; 32 rows per block, 256 threads.
__global__ __launch_bounds__(256) void k_gemm(const float* __restrict__ A,
                                              const float* __restrict__ W,
                                              float* __restrict__ C, int n){
  __shared__ float Ws[32][128];
  __shared__ float As[32][33];   // +1 pad
  const int row0 = blockIdx.x * 32;
  const int col  = threadIdx.x & 127;
  const int r2   = threadIdx.x >> 7;  // 0..1
  float acc[16];
  #pragma unroll
  for (int i = 0; i < 16; i++) acc[i] = 0.f;

  for (int kt = 0; kt < 128; kt += 32){
    #pragma unroll
    for (int j = 0; j < 16; j++){
      int idx = threadIdx.x + j * 256;        // 0..4095
      int kk = idx >> 7, cc = idx & 127;
      Ws[kk][cc] = W[(kt + kk) * DD + cc];
    }
    #pragma unroll
    for (int j = 0; j < 4; j++){
      int idx = threadIdx.x + j * 256;        // 0..1023
      int rr = idx >> 5, kk = idx & 31;
      int row = row0 + rr;
      As[rr][kk] = (row < n) ? A[(long)row * DD + kt + kk] : 0.f;
    }
    __syncthreads();
    #pragma unroll
    for (int k = 0; k < 32; k++){
      float wv = Ws[k][col];
      #pragma unroll
      for (int rr = 0; rr < 16; rr++)
        acc[rr] += As[r2 + rr * 2][k] * wv;
    }
    __syncthreads();
  }
  #pragma unroll
  for (int rr = 0; rr < 16; rr++){
    int row = row0 + r2 + rr * 2;
    if (row < n) C[(long)row * DD + col] = acc[rr];
  }
}

// out[dst] += xw[src] * dinv[src]*dinv[dst]; 32 threads/edge, float4 gather.
__global__ void k_agg(const float* __restrict__ xw, const int* __restrict__ src,
                      const int* __restrict__ dst, const float* __restrict__ dinv,
                      float* __restrict__ out, int E){
  long tid = (long)blockIdx.x * blockDim.x + threadIdx.x;
  int e = (int)(tid >> 5);
  if (e >= E) return;
  int c = ((int)tid & 31) * 4;
  int s = src[e], d = dst[e];
  float nrm = dinv[s] * dinv[d];
  const float4 v = *(const float4*)(xw + (long)s * DD + c);
  float* o = out + (long)d * DD + c;
  atomicAdd(o + 0, v.x * nrm);
  atomicAdd(o + 1, v.y * nrm);
  atomicAdd(o + 2, v.z * nrm);
  atomicAdd(o + 3, v.w * nrm);
}

// out = elu(out + xw*dinv^2 + b)
__global__ void k_epilogue(float* __restrict__ out, const float* __restrict__ xw,
                           const float* __restrict__ dinv, const float* __restrict__ b,
                           int n){
  long i = (long)blockIdx.x * blockDim.x + threadIdx.x;
  if (i >= (long)n * DD) return;
  int r = (int)(i >> 7), c = (int)i & 127;
  float di = dinv[r];
  float v = out[i] + xw[i] * di * di + b[c];
  out[i] = v > 0.f ? v : expm1f(v);
}

// outf[idx[r]] = h[r]
__global__ void k_scatter(const float* __restrict__ h, const int* __restrict__ idx,
                          float* __restrict__ outf, int npool){
  long i = (long)blockIdx.x * blockDim.x + threadIdx.x;
  if (i >= (long)npool * DD) return;
  int r = (int)(i >> 7), c = (int)i & 127;
  outf[(long)idx[r] * DD + c] = h[i];
}

extern "C" void kernel_launch(void* const* d_in, const int* in_sizes, int n_in,
                              void* d_out, int out_size, void* d_ws, size_t ws_size,
                              hipStream_t stream) {
  const int*   edge   = (const int*)d_in[1];
  const float* px     = (const float*)d_in[2];
  const int*   pedge  = (const int*)d_in[3];
  const int*   unpool = (const int*)d_in[4];
  const float* W0 = (const float*)d_in[5]; const float* b0 = (const float*)d_in[6];
  const float* W1 = (const float*)d_in[7]; const float* b1 = (const float*)d_in[8];
  const float* W2 = (const float*)d_in[9]; const float* b2 = (const float*)d_in[10];
  const int n_full = in_sizes[0] / DD;
  const int E_full = in_sizes[1] / 2;
  const int n_pool = in_sizes[2] / DD;
  const int E_pool = in_sizes[3] / 2;
  float* out = (float*)d_out;

  // workspace layout
  char* w = (char*)d_ws;
  size_t off = 0;
  auto alloc = [&](size_t bytes) -> float* {
    float* p = (float*)(w + off);
    off += (bytes + 255) / 256 * 256;
    return p;
  };
  float* dinv_p = alloc((size_t)n_pool * 4);
  float* dinv_f = alloc((size_t)n_full * 4);
  const size_t big = (size_t)n_full * DD * 4;
  float* bufA = alloc(big);
  float* bufB = alloc(big);
  float* bufC = alloc(big);

  float* xw0  = bufA; float* h0 = bufB; float* hw1 = bufC;
  float* xw1f = bufA; float* y1 = bufB; float* xw2 = bufC;

  // degrees -> dinv (pool + full)
  k_init_ones<<<cdiv(n_pool,256),256,0,stream>>>(dinv_p, n_pool);
  k_deg<<<cdiv(E_pool,256),256,0,stream>>>(pedge + E_pool, dinv_p, E_pool);
  k_rsqrt<<<cdiv(n_pool,256),256,0,stream>>>(dinv_p, n_pool);
  k_init_ones<<<cdiv(n_full,256),256,0,stream>>>(dinv_f, n_full);
  k_deg<<<cdiv(E_full,256),256,0,stream>>>(edge + E_full, dinv_f, E_full);
  k_rsqrt<<<cdiv(n_full,256),256,0,stream>>>(dinv_f, n_full);

  // conv0 on pooled graph
  k_gemm<<<cdiv(n_pool,32),256,0,stream>>>(px, W0, xw0, n_pool);
  hipMemsetAsync(h0, 0, (size_t)n_pool * DD * 4, stream);
  k_agg<<<cdiv((long)E_pool*32,256),256,0,stream>>>(xw0, pedge, pedge + E_pool, dinv_p, h0, E_pool);
  k_epilogue<<<cdiv((long)n_pool*DD,256),256,0,stream>>>(h0, xw0, dinv_p, b0, n_pool);

  // conv1 on full graph (features sparse: only unpooled rows nonzero)
  k_gemm<<<cdiv(n_pool,32),256,0,stream>>>(h0, W1, hw1, n_pool);
  hipMemsetAsync(xw1f, 0, big, stream);
  k_scatter<<<cdiv((long)n_pool*DD,256),256,0,stream>>>(hw1, unpool, xw1f, n_pool);
  hipMemsetAsync(y1, 0, big, stream);
  k_agg<<<cdiv((long)E_full*32,256),256,0,stream>>>(xw1f, edge, edge + E_full, dinv_f, y1, E_full);
  k_epilogue<<<cdiv((long)n_full*DD,256),256,0,stream>>>(y1, xw1f, dinv_f, b1, n_full);

  // conv2 on full graph
  k_gemm<<<cdiv(n_full,32),256,0,stream>>>(y1, W2, xw2, n_full);
  hipMemsetAsync(out, 0, (size_t)out_size * 4, stream);
  k_agg<<<cdiv((long)E_full*32,256),256,0,stream>>>(xw2, edge, edge + E_full, dinv_f, out, E_full);
  k_epilogue<<<cdiv((long)n_full*DD,256),256,0,stream>>>(out, xw2, dinv_f, b2, n_full);
}

// Round 2
// 672.064 us; speedup vs baseline: 4.0436x; 4.0436x over previous
//
#include <hip/hip_runtime.h>
#include <math.h>

#define DD 128

static inline int cdiv(long a, long b){ return (int)((a + b - 1) / b); }

// ---------- degree / CSR build ----------

__global__ void k_count(const int* __restrict__ dst, int* __restrict__ cnt, int E){
  int e = blockIdx.x * blockDim.x + threadIdx.x;
  if (e < E) atomicAdd(&cnt[dst[e]], 1);
}

__global__ void k_dinv(const int* __restrict__ cnt, float* __restrict__ dinv, int n){
  int i = blockIdx.x * blockDim.x + threadIdx.x;
  if (i < n) dinv[i] = rsqrtf((float)(cnt[i] + 1));   // +1 self loop
}

// single-block exclusive scan: rptr[0..n] from cnt[0..n-1]
__global__ __launch_bounds__(1024) void k_scan(const int* __restrict__ cnt,
                                               int* __restrict__ rptr, int n){
  __shared__ int sums[1024];
  int t = threadIdx.x;
  int chunk = (n + 1023) >> 10;
  int b0 = t * chunk, b1 = min(b0 + chunk, n);
  int s = 0;
  for (int i = b0; i < b1; i++) s += cnt[i];
  sums[t] = s; __syncthreads();
  for (int off = 1; off < 1024; off <<= 1){
    int v = (t >= off) ? sums[t - off] : 0;
    __syncthreads();
    sums[t] += v;
    __syncthreads();
  }
  int run = (t == 0) ? 0 : sums[t - 1];
  for (int i = b0; i < b1; i++){ rptr[i] = run; run += cnt[i]; }
  if (b1 == n) rptr[n] = run;   // duplicates write same value; benign
}

__global__ void k_copy_int(const int* __restrict__ a, int* __restrict__ b, int n){
  int i = blockIdx.x * blockDim.x + threadIdx.x;
  if (i < n) b[i] = a[i];
}

__global__ void k_fill(const int* __restrict__ src, const int* __restrict__ dst,
                       int* __restrict__ cursor, int* __restrict__ csrc, int E){
  int e = blockIdx.x * blockDim.x + threadIdx.x;
  if (e < E){
    int p = atomicAdd(&cursor[dst[e]], 1);
    csrc[p] = src[e];
  }
}

__global__ void k_inv_scatter(const int* __restrict__ unpool, int* __restrict__ inv, int npool){
  int i = blockIdx.x * blockDim.x + threadIdx.x;
  if (i < npool) inv[unpool[i]] = i;
}

// ---------- GEMM: C[n,128] = A[n,128] @ W[128,128] ----------
__global__ __launch_bounds__(256) void k_gemm(const float* __restrict__ A,
                                              const float* __restrict__ W,
                                              float* __restrict__ C, int n){
  __shared__ float Ws[32][128];
  __shared__ float As[32][33];
  const int row0 = blockIdx.x * 32;
  const int col  = threadIdx.x & 127;
  const int r2   = threadIdx.x >> 7;
  float acc[16];
  #pragma unroll
  for (int i = 0; i < 16; i++) acc[i] = 0.f;

  for (int kt = 0; kt < 128; kt += 32){
    #pragma unroll
    for (int j = 0; j < 16; j++){
      int idx = threadIdx.x + j * 256;
      int kk = idx >> 7, cc = idx & 127;
      Ws[kk][cc] = W[(kt + kk) * DD + cc];
    }
    #pragma unroll
    for (int j = 0; j < 4; j++){
      int idx = threadIdx.x + j * 256;
      int rr = idx >> 5, kk = idx & 31;
      int row = row0 + rr;
      As[rr][kk] = (row < n) ? A[(long)row * DD + kt + kk] : 0.f;
    }
    __syncthreads();
    #pragma unroll
    for (int k = 0; k < 32; k++){
      float wv = Ws[k][col];
      #pragma unroll
      for (int rr = 0; rr < 16; rr++)
        acc[rr] += As[r2 + rr * 2][k] * wv;
    }
    __syncthreads();
  }
  #pragma unroll
  for (int rr = 0; rr < 16; rr++){
    int row = row0 + r2 + rr * 2;
    if (row < n) C[(long)row * DD + col] = acc[rr];
  }
}

// ---------- fused CSR aggregation + self-loop + bias + ELU ----------
// one wave (64 lanes) per dst row, 2 floats per lane
__global__ __launch_bounds__(256) void k_agg_csr(const float* __restrict__ xw,
    const int* __restrict__ rptr, const int* __restrict__ csrc,
    const float* __restrict__ dinv, const float* __restrict__ b,
    float* __restrict__ out, int n){
  int row = blockIdx.x * 4 + (threadIdx.x >> 6);
  if (row >= n) return;
  int c = (threadIdx.x & 63) * 2;
  float ax = 0.f, ay = 0.f;
  int j0 = rptr[row], j1 = rptr[row + 1];
  for (int j = j0; j < j1; j++){
    int s = csrc[j];
    float w = dinv[s];
    float2 v = *(const float2*)(xw + (long)s * DD + c);
    ax += v.x * w; ay += v.y * w;
  }
  float dd = dinv[row];
  float2 sv = *(const float2*)(xw + (long)row * DD + c);
  float2 bb = *(const float2*)(b + c);
  float vx = ax * dd + sv.x * dd * dd + bb.x;
  float vy = ay * dd + sv.y * dd * dd + bb.y;
  vx = vx > 0.f ? vx : expm1f(vx);
  vy = vy > 0.f ? vy : expm1f(vy);
  *(float2*)(out + (long)row * DD + c) = make_float2(vx, vy);
}

// sparse-input variant: features live in hw[n_pool rows], full idx -> pool row via inv (or -1)
__global__ __launch_bounds__(256) void k_agg_csr_sp(const float* __restrict__ hw,
    const int* __restrict__ inv, const int* __restrict__ rptr, const int* __restrict__ csrc,
    const float* __restrict__ dinv, const float* __restrict__ b,
    float* __restrict__ out, int n){
  int row = blockIdx.x * 4 + (threadIdx.x >> 6);
  if (row >= n) return;
  int c = (threadIdx.x & 63) * 2;
  float ax = 0.f, ay = 0.f;
  int j0 = rptr[row], j1 = rptr[row + 1];
  for (int j = j0; j < j1; j++){
    int s = csrc[j];
    int p = inv[s];
    if (p >= 0){
      float w = dinv[s];
      float2 v = *(const float2*)(hw + (long)p * DD + c);
      ax += v.x * w; ay += v.y * w;
    }
  }
  float dd = dinv[row];
  int pr = inv[row];
  float sx = 0.f, sy = 0.f;
  if (pr >= 0){
    float2 sv = *(const float2*)(hw + (long)pr * DD + c);
    sx = sv.x; sy = sv.y;
  }
  float2 bb = *(const float2*)(b + c);
  float vx = ax * dd + sx * dd * dd + bb.x;
  float vy = ay * dd + sy * dd * dd + bb.y;
  vx = vx > 0.f ? vx : expm1f(vx);
  vy = vy > 0.f ? vy : expm1f(vy);
  *(float2*)(out + (long)row * DD + c) = make_float2(vx, vy);
}

extern "C" void kernel_launch(void* const* d_in, const int* in_sizes, int n_in,
                              void* d_out, int out_size, void* d_ws, size_t ws_size,
                              hipStream_t stream) {
  const int*   edge   = (const int*)d_in[1];
  const float* px     = (const float*)d_in[2];
  const int*   pedge  = (const int*)d_in[3];
  const int*   unpool = (const int*)d_in[4];
  const float* W0 = (const float*)d_in[5]; const float* b0 = (const float*)d_in[6];
  const float* W1 = (const float*)d_in[7]; const float* b1 = (const float*)d_in[8];
  const float* W2 = (const float*)d_in[9]; const float* b2 = (const float*)d_in[10];
  const int n_full = in_sizes[0] / DD;
  const int E_full = in_sizes[1] / 2;
  const int n_pool = in_sizes[2] / DD;
  const int E_pool = in_sizes[3] / 2;
  float* out = (float*)d_out;

  // ---- workspace layout ----
  char* w = (char*)d_ws;
  size_t off = 0;
  auto alloc = [&](size_t bytes) -> void* {
    void* p = (void*)(w + off);
    off += (bytes + 255) / 256 * 256;
    return p;
  };
  float* dinv_p = (float*)alloc((size_t)n_pool * 4);
  float* dinv_f = (float*)alloc((size_t)n_full * 4);
  int* cnt_p  = (int*)alloc((size_t)n_pool * 4);
  int* cnt_f  = (int*)alloc((size_t)n_full * 4);
  int* rptr_p = (int*)alloc((size_t)(n_pool + 1) * 4);
  int* rptr_f = (int*)alloc((size_t)(n_full + 1) * 4);
  int* csrc_p = (int*)alloc((size_t)E_pool * 4);
  int* csrc_f = (int*)alloc((size_t)E_full * 4);
  int* invm   = (int*)alloc((size_t)n_full * 4);
  const size_t big = (size_t)n_full * DD * 4;
  float* bufA = (float*)alloc(big);
  float* bufB = (float*)alloc(big);

  const int* src_f = edge;          const int* dst_f = edge + E_full;
  const int* src_p = pedge;         const int* dst_p = pedge + E_pool;

  // ---- CSR build (both graphs) + inverse unpool map ----
  hipMemsetAsync(cnt_p, 0, (size_t)n_pool * 4, stream);
  hipMemsetAsync(cnt_f, 0, (size_t)n_full * 4, stream);
  hipMemsetAsync(invm, 0xFF, (size_t)n_full * 4, stream);   // -1
  k_count<<<cdiv(E_pool,256),256,0,stream>>>(dst_p, cnt_p, E_pool);
  k_count<<<cdiv(E_full,256),256,0,stream>>>(dst_f, cnt_f, E_full);
  k_dinv<<<cdiv(n_pool,256),256,0,stream>>>(cnt_p, dinv_p, n_pool);
  k_dinv<<<cdiv(n_full,256),256,0,stream>>>(cnt_f, dinv_f, n_full);
  k_scan<<<1,1024,0,stream>>>(cnt_p, rptr_p, n_pool);
  k_scan<<<1,1024,0,stream>>>(cnt_f, rptr_f, n_full);
  // reuse cnt arrays as cursors
  k_copy_int<<<cdiv(n_pool,256),256,0,stream>>>(rptr_p, cnt_p, n_pool);
  k_copy_int<<<cdiv(n_full,256),256,0,stream>>>(rptr_f, cnt_f, n_full);
  k_fill<<<cdiv(E_pool,256),256,0,stream>>>(src_p, dst_p, cnt_p, csrc_p, E_pool);
  k_fill<<<cdiv(E_full,256),256,0,stream>>>(src_f, dst_f, cnt_f, csrc_f, E_full);
  k_inv_scatter<<<cdiv(n_pool,256),256,0,stream>>>(unpool, invm, n_pool);

  float* xw0 = bufA;   // pool rows
  float* h0  = bufB;   // pool rows
  float* hw1 = bufA;   // pool rows (xw0 dead)
  float* y1  = bufB;   // full rows (h0 dead after gemm)
  float* xw2 = bufA;   // full rows (hw1 dead)

  // conv0 (pooled graph), fused agg+ELU
  k_gemm<<<cdiv(n_pool,32),256,0,stream>>>(px, W0, xw0, n_pool);
  k_agg_csr<<<cdiv(n_pool,4),256,0,stream>>>(xw0, rptr_p, csrc_p, dinv_p, b0, h0, n_pool);

  // conv1 (full graph, sparse input via inverse map)
  k_gemm<<<cdiv(n_pool,32),256,0,stream>>>(h0, W1, hw1, n_pool);
  k_agg_csr_sp<<<cdiv(n_full,4),256,0,stream>>>(hw1, invm, rptr_f, csrc_f, dinv_f, b1, y1, n_full);

  // conv2 (full graph, dense)
  k_gemm<<<cdiv(n_full,32),256,0,stream>>>(y1, W2, xw2, n_full);
  k_agg_csr<<<cdiv(n_full,4),256,0,stream>>>(xw2, rptr_f, csrc_f, dinv_f, b2, out, n_full);
}

// Round 3
// 480.943 us; speedup vs baseline: 5.6505x; 1.3974x over previous
//
#include <hip/hip_runtime.h>
#include <math.h>

#define DD 128

static inline int cdiv(long a, long b){ return (int)((a + b - 1) / b); }

// ---------- degree / CSR build ----------

__global__ void k_count(const int* __restrict__ dst, int* __restrict__ cnt, int E){
  int e = blockIdx.x * blockDim.x + threadIdx.x;
  if (e < E) atomicAdd(&cnt[dst[e]], 1);
}

__global__ void k_dinv(const int* __restrict__ cnt, float* __restrict__ dinv, int n){
  int i = blockIdx.x * blockDim.x + threadIdx.x;
  if (i < n) dinv[i] = rsqrtf((float)(cnt[i] + 1));   // +1 self loop
}

// single-block exclusive scan: rptr[0..n] from cnt[0..n-1]
__global__ __launch_bounds__(1024) void k_scan(const int* __restrict__ cnt,
                                               int* __restrict__ rptr, int n){
  __shared__ int sums[1024];
  int t = threadIdx.x;
  int chunk = (n + 1023) >> 10;
  int b0 = t * chunk, b1 = min(b0 + chunk, n);
  int s = 0;
  for (int i = b0; i < b1; i++) s += cnt[i];
  sums[t] = s; __syncthreads();
  for (int off = 1; off < 1024; off <<= 1){
    int v = (t >= off) ? sums[t - off] : 0;
    __syncthreads();
    sums[t] += v;
    __syncthreads();
  }
  int run = (t == 0) ? 0 : sums[t - 1];
  for (int i = b0; i < b1; i++){ rptr[i] = run; run += cnt[i]; }
  if (b1 == n) rptr[n] = run;
}

__global__ void k_copy_int(const int* __restrict__ a, int* __restrict__ b, int n){
  int i = blockIdx.x * blockDim.x + threadIdx.x;
  if (i < n) b[i] = a[i];
}

__global__ void k_fill(const int* __restrict__ src, const int* __restrict__ dst,
                       int* __restrict__ cursor, int* __restrict__ csrc, int E){
  int e = blockIdx.x * blockDim.x + threadIdx.x;
  if (e < E){
    int p = atomicAdd(&cursor[dst[e]], 1);
    csrc[p] = src[e];
  }
}

__global__ void k_inv_scatter(const int* __restrict__ unpool, int* __restrict__ inv, int npool){
  int i = blockIdx.x * blockDim.x + threadIdx.x;
  if (i < npool) inv[unpool[i]] = i;
}

// ---------- GEMM: C[n,128] = A[n,128] @ W[128,128] ----------
// 64 rows x 128 cols per block; 256 threads; 4x8 register tile per thread.
__global__ __launch_bounds__(256) void k_gemm(const float* __restrict__ A,
                                              const float* __restrict__ W,
                                              float* __restrict__ C, int n){
  __shared__ float As[16][68];    // [k][row], pad 68 -> 272B row stride (16B aligned)
  __shared__ float Ws[16][128];   // [k][col]
  const int t    = threadIdx.x;
  const int row0 = blockIdx.x * 64;
  const int tc   = t & 15;        // col group: cols tc*8 .. +7
  const int tr   = t >> 4;        // row group: rows tr*4 .. +3
  const int sr   = t >> 2;        // staging: A row 0..63
  const int sk   = (t & 3) * 4;   // staging: k offset {0,4,8,12}

  float acc[4][8];
  #pragma unroll
  for (int i = 0; i < 4; i++)
    #pragma unroll
    for (int j = 0; j < 8; j++) acc[i][j] = 0.f;

  for (int kt = 0; kt < 128; kt += 16){
    float4 av = make_float4(0.f, 0.f, 0.f, 0.f);
    int arow = row0 + sr;
    if (arow < n) av = *(const float4*)(A + (long)arow * DD + kt + sk);
    const float4 wv0 = *(const float4*)(W + (long)(kt + tr) * DD + tc * 8);
    const float4 wv1 = *(const float4*)(W + (long)(kt + tr) * DD + tc * 8 + 4);
    __syncthreads();
    As[sk + 0][sr] = av.x;
    As[sk + 1][sr] = av.y;
    As[sk + 2][sr] = av.z;
    As[sk + 3][sr] = av.w;
    *(float4*)(&Ws[tr][tc * 8])     = wv0;
    *(float4*)(&Ws[tr][tc * 8 + 4]) = wv1;
    __syncthreads();
    #pragma unroll
    for (int k = 0; k < 16; k++){
      const float4 a4 = *(const float4*)(&As[k][tr * 4]);
      const float4 w0 = *(const float4*)(&Ws[k][tc * 8]);
      const float4 w1 = *(const float4*)(&Ws[k][tc * 8 + 4]);
      const float ar[4] = {a4.x, a4.y, a4.z, a4.w};
      const float wr[8] = {w0.x, w0.y, w0.z, w0.w, w1.x, w1.y, w1.z, w1.w};
      #pragma unroll
      for (int i = 0; i < 4; i++)
        #pragma unroll
        for (int j = 0; j < 8; j++)
          acc[i][j] += ar[i] * wr[j];
    }
  }
  #pragma unroll
  for (int i = 0; i < 4; i++){
    int row = row0 + tr * 4 + i;
    if (row < n){
      *(float4*)(C + (long)row * DD + tc * 8)     = make_float4(acc[i][0], acc[i][1], acc[i][2], acc[i][3]);
      *(float4*)(C + (long)row * DD + tc * 8 + 4) = make_float4(acc[i][4], acc[i][5], acc[i][6], acc[i][7]);
    }
  }
}

// ---------- fused CSR aggregation + self-loop + bias + ELU ----------
// one wave (64 lanes) per dst row, 2 floats per lane, edge loop unrolled x2
__global__ __launch_bounds__(256) void k_agg_csr(const float* __restrict__ xw,
    const int* __restrict__ rptr, const int* __restrict__ csrc,
    const float* __restrict__ dinv, const float* __restrict__ b,
    float* __restrict__ out, int n){
  int row = blockIdx.x * 4 + (threadIdx.x >> 6);
  if (row >= n) return;
  int c = (threadIdx.x & 63) * 2;
  float ax = 0.f, ay = 0.f, bx = 0.f, by = 0.f;
  int j0 = rptr[row], j1 = rptr[row + 1];
  int j = j0;
  for (; j + 1 < j1; j += 2){
    int s0 = csrc[j], s1 = csrc[j + 1];
    float w0 = dinv[s0], w1 = dinv[s1];
    float2 v0 = *(const float2*)(xw + (long)s0 * DD + c);
    float2 v1 = *(const float2*)(xw + (long)s1 * DD + c);
    ax += v0.x * w0; ay += v0.y * w0;
    bx += v1.x * w1; by += v1.y * w1;
  }
  if (j < j1){
    int s0 = csrc[j];
    float w0 = dinv[s0];
    float2 v0 = *(const float2*)(xw + (long)s0 * DD + c);
    ax += v0.x * w0; ay += v0.y * w0;
  }
  ax += bx; ay += by;
  float dd = dinv[row];
  float2 sv = *(const float2*)(xw + (long)row * DD + c);
  float2 bb = *(const float2*)(b + c);
  float vx = ax * dd + sv.x * dd * dd + bb.x;
  float vy = ay * dd + sv.y * dd * dd + bb.y;
  vx = vx > 0.f ? vx : expm1f(vx);
  vy = vy > 0.f ? vy : expm1f(vy);
  *(float2*)(out + (long)row * DD + c) = make_float2(vx, vy);
}

// sparse-input variant: features in hw[n_pool rows]; full idx -> pool row via inv (or -1)
__global__ __launch_bounds__(256) void k_agg_csr_sp(const float* __restrict__ hw,
    const int* __restrict__ inv, const int* __restrict__ rptr, const int* __restrict__ csrc,
    const float* __restrict__ dinv, const float* __restrict__ b,
    float* __restrict__ out, int n){
  int row = blockIdx.x * 4 + (threadIdx.x >> 6);
  if (row >= n) return;
  int c = (threadIdx.x & 63) * 2;
  float ax = 0.f, ay = 0.f;
  int j0 = rptr[row], j1 = rptr[row + 1];
  for (int j = j0; j < j1; j++){
    int s = csrc[j];
    int p = inv[s];
    if (p >= 0){
      float w = dinv[s];
      float2 v = *(const float2*)(hw + (long)p * DD + c);
      ax += v.x * w; ay += v.y * w;
    }
  }
  float dd = dinv[row];
  int pr = inv[row];
  float sx = 0.f, sy = 0.f;
  if (pr >= 0){
    float2 sv = *(const float2*)(hw + (long)pr * DD + c);
    sx = sv.x; sy = sv.y;
  }
  float2 bb = *(const float2*)(b + c);
  float vx = ax * dd + sx * dd * dd + bb.x;
  float vy = ay * dd + sy * dd * dd + bb.y;
  vx = vx > 0.f ? vx : expm1f(vx);
  vy = vy > 0.f ? vy : expm1f(vy);
  *(float2*)(out + (long)row * DD + c) = make_float2(vx, vy);
}

extern "C" void kernel_launch(void* const* d_in, const int* in_sizes, int n_in,
                              void* d_out, int out_size, void* d_ws, size_t ws_size,
                              hipStream_t stream) {
  const int*   edge   = (const int*)d_in[1];
  const float* px     = (const float*)d_in[2];
  const int*   pedge  = (const int*)d_in[3];
  const int*   unpool = (const int*)d_in[4];
  const float* W0 = (const float*)d_in[5]; const float* b0 = (const float*)d_in[6];
  const float* W1 = (const float*)d_in[7]; const float* b1 = (const float*)d_in[8];
  const float* W2 = (const float*)d_in[9]; const float* b2 = (const float*)d_in[10];
  const int n_full = in_sizes[0] / DD;
  const int E_full = in_sizes[1] / 2;
  const int n_pool = in_sizes[2] / DD;
  const int E_pool = in_sizes[3] / 2;
  float* out = (float*)d_out;

  // ---- workspace layout ----
  char* w = (char*)d_ws;
  size_t off = 0;
  auto alloc = [&](size_t bytes) -> void* {
    void* p = (void*)(w + off);
    off += (bytes + 255) / 256 * 256;
    return p;
  };
  float* dinv_p = (float*)alloc((size_t)n_pool * 4);
  float* dinv_f = (float*)alloc((size_t)n_full * 4);
  int* cnt_p  = (int*)alloc((size_t)n_pool * 4);
  int* cnt_f  = (int*)alloc((size_t)n_full * 4);
  int* rptr_p = (int*)alloc((size_t)(n_pool + 1) * 4);
  int* rptr_f = (int*)alloc((size_t)(n_full + 1) * 4);
  int* csrc_p = (int*)alloc((size_t)E_pool * 4);
  int* csrc_f = (int*)alloc((size_t)E_full * 4);
  int* invm   = (int*)alloc((size_t)n_full * 4);
  const size_t big = (size_t)n_full * DD * 4;
  float* bufA = (float*)alloc(big);
  float* bufB = (float*)alloc(big);

  const int* src_f = edge;          const int* dst_f = edge + E_full;
  const int* src_p = pedge;         const int* dst_p = pedge + E_pool;

  // ---- CSR build (both graphs) + inverse unpool map ----
  hipMemsetAsync(cnt_p, 0, (size_t)n_pool * 4, stream);
  hipMemsetAsync(cnt_f, 0, (size_t)n_full * 4, stream);
  hipMemsetAsync(invm, 0xFF, (size_t)n_full * 4, stream);   // -1
  k_count<<<cdiv(E_pool,256),256,0,stream>>>(dst_p, cnt_p, E_pool);
  k_count<<<cdiv(E_full,256),256,0,stream>>>(dst_f, cnt_f, E_full);
  k_dinv<<<cdiv(n_pool,256),256,0,stream>>>(cnt_p, dinv_p, n_pool);
  k_dinv<<<cdiv(n_full,256),256,0,stream>>>(cnt_f, dinv_f, n_full);
  k_scan<<<1,1024,0,stream>>>(cnt_p, rptr_p, n_pool);
  k_scan<<<1,1024,0,stream>>>(cnt_f, rptr_f, n_full);
  k_copy_int<<<cdiv(n_pool,256),256,0,stream>>>(rptr_p, cnt_p, n_pool);
  k_copy_int<<<cdiv(n_full,256),256,0,stream>>>(rptr_f, cnt_f, n_full);
  k_fill<<<cdiv(E_pool,256),256,0,stream>>>(src_p, dst_p, cnt_p, csrc_p, E_pool);
  k_fill<<<cdiv(E_full,256),256,0,stream>>>(src_f, dst_f, cnt_f, csrc_f, E_full);
  k_inv_scatter<<<cdiv(n_pool,256),256,0,stream>>>(unpool, invm, n_pool);

  float* xw0 = bufA;   // pool rows
  float* h0  = bufB;   // pool rows
  float* hw1 = bufA;   // pool rows (xw0 dead)
  float* y1  = bufB;   // full rows (h0 dead after gemm)
  float* xw2 = bufA;   // full rows (hw1 dead)

  // conv0 (pooled graph), fused agg+bias+ELU
  k_gemm<<<cdiv(n_pool,64),256,0,stream>>>(px, W0, xw0, n_pool);
  k_agg_csr<<<cdiv(n_pool,4),256,0,stream>>>(xw0, rptr_p, csrc_p, dinv_p, b0, h0, n_pool);

  // conv1 (full graph, sparse input via inverse map)
  k_gemm<<<cdiv(n_pool,64),256,0,stream>>>(h0, W1, hw1, n_pool);
  k_agg_csr_sp<<<cdiv(n_full,4),256,0,stream>>>(hw1, invm, rptr_f, csrc_f, dinv_f, b1, y1, n_full);

  // conv2 (full graph, dense)
  k_gemm<<<cdiv(n_full,64),256,0,stream>>>(y1, W2, xw2, n_full);
  k_agg_csr<<<cdiv(n_full,4),256,0,stream>>>(xw2, rptr_f, csrc_f, dinv_f, b2, out, n_full);
}

// Round 4
// 391.172 us; speedup vs baseline: 6.9473x; 1.2295x over previous
//
#include <hip/hip_runtime.h>
#include <math.h>

#define DD 128

static inline int cdiv(long a, long b){ return (int)((a + b - 1) / b); }

// ---------- degree count ----------

__global__ void k_count(const int* __restrict__ dst, int* __restrict__ cnt, int E){
  int e = blockIdx.x * blockDim.x + threadIdx.x;
  if (e < E) atomicAdd(&cnt[dst[e]], 1);
}

// ---------- hierarchical scan (full + pool segments in one launch) ----------
// phase 1: per-block (1024 elems) sums
__global__ __launch_bounds__(256) void k_bsum(
    const int* __restrict__ cnt_f, int nf, const int* __restrict__ cnt_p, int np,
    int* __restrict__ bsum_f, int* __restrict__ bsum_p, int nbf){
  const int* cnt; int n; int* bsum; int b;
  if ((int)blockIdx.x < nbf){ cnt = cnt_f; n = nf; bsum = bsum_f; b = blockIdx.x; }
  else                      { cnt = cnt_p; n = np; bsum = bsum_p; b = blockIdx.x - nbf; }
  __shared__ int s[256];
  int t = threadIdx.x;
  long base = (long)b * 1024 + t * 4;
  int v = 0;
  if (base + 3 < n){ int4 q = *(const int4*)(cnt + base); v = q.x + q.y + q.z + q.w; }
  else { for (int j = 0; j < 4; j++) if (base + j < n) v += cnt[base + j]; }
  s[t] = v; __syncthreads();
  for (int off = 128; off > 0; off >>= 1){ if (t < off) s[t] += s[t + off]; __syncthreads(); }
  if (t == 0) bsum[b] = s[0];
}

// phase 2: exclusive scan of block sums (both segments, each <= 128 blocks)
__global__ __launch_bounds__(128) void k_scan_b(int* __restrict__ bsum_f, int nbf,
                                                int* __restrict__ bsum_p, int nbp){
  __shared__ int s[128];
  int t = threadIdx.x;
  int v = (t < nbf) ? bsum_f[t] : 0;
  s[t] = v; __syncthreads();
  for (int off = 1; off < 128; off <<= 1){ int u = (t >= off) ? s[t - off] : 0; __syncthreads(); s[t] += u; __syncthreads(); }
  if (t < nbf) bsum_f[t] = s[t] - v;
  __syncthreads();
  int v2 = (t < nbp) ? bsum_p[t] : 0;
  s[t] = v2; __syncthreads();
  for (int off = 1; off < 128; off <<= 1){ int u = (t >= off) ? s[t - off] : 0; __syncthreads(); s[t] += u; __syncthreads(); }
  if (t < nbp) bsum_p[t] = s[t] - v2;
}

// phase 3: local scan + write rptr, cursor copy, and dinv (fused)
__global__ __launch_bounds__(256) void k_scan_f(
    const int* __restrict__ cnt_f, int nf, const int* __restrict__ bsum_f,
    const int* __restrict__ cnt_p, int np, const int* __restrict__ bsum_p,
    int* __restrict__ rptr_f, int* __restrict__ cur_f, float* __restrict__ dinv_f,
    int* __restrict__ rptr_p, int* __restrict__ cur_p, float* __restrict__ dinv_p,
    int nbf, int Ef, int Ep){
  const int* cnt; const int* bsum; int* rptr; int* cur; float* dinv; int n; int b;
  if ((int)blockIdx.x < nbf){ cnt=cnt_f; bsum=bsum_f; rptr=rptr_f; cur=cur_f; dinv=dinv_f; n=nf; b=blockIdx.x; }
  else                      { cnt=cnt_p; bsum=bsum_p; rptr=rptr_p; cur=cur_p; dinv=dinv_p; n=np; b=blockIdx.x-nbf; }
  __shared__ int s[256];
  int t = threadIdx.x;
  long base = (long)b * 1024 + t * 4;
  int c0=0,c1=0,c2=0,c3=0;
  if (base + 3 < n){ int4 q = *(const int4*)(cnt + base); c0=q.x; c1=q.y; c2=q.z; c3=q.w; }
  else {
    if (base + 0 < n) c0 = cnt[base + 0];
    if (base + 1 < n) c1 = cnt[base + 1];
    if (base + 2 < n) c2 = cnt[base + 2];
  }
  int tsum = c0 + c1 + c2 + c3;
  s[t] = tsum; __syncthreads();
  for (int off = 1; off < 256; off <<= 1){ int u = (t >= off) ? s[t - off] : 0; __syncthreads(); s[t] += u; __syncthreads(); }
  int run = bsum[b] + s[t] - tsum;
  int r0 = run, r1 = r0 + c0, r2 = r1 + c1, r3 = r2 + c2;
  if (base + 3 < n){
    *(int4*)(rptr + base) = make_int4(r0, r1, r2, r3);
    *(int4*)(cur + base)  = make_int4(r0, r1, r2, r3);
    dinv[base + 0] = rsqrtf((float)(c0 + 1));
    dinv[base + 1] = rsqrtf((float)(c1 + 1));
    dinv[base + 2] = rsqrtf((float)(c2 + 1));
    dinv[base + 3] = rsqrtf((float)(c3 + 1));
  } else {
    if (base + 0 < n){ rptr[base+0]=r0; cur[base+0]=r0; dinv[base+0]=rsqrtf((float)(c0+1)); }
    if (base + 1 < n){ rptr[base+1]=r1; cur[base+1]=r1; dinv[base+1]=rsqrtf((float)(c1+1)); }
    if (base + 2 < n){ rptr[base+2]=r2; cur[base+2]=r2; dinv[base+2]=rsqrtf((float)(c2+1)); }
  }
  if (blockIdx.x == 0 && t == 0){ rptr_f[nf] = Ef; rptr_p[np] = Ep; }
}

__global__ void k_fill(const int* __restrict__ src, const int* __restrict__ dst,
                       int* __restrict__ cursor, int* __restrict__ csrc, int E){
  int e = blockIdx.x * blockDim.x + threadIdx.x;
  if (e < E){
    int p = atomicAdd(&cursor[dst[e]], 1);
    csrc[p] = src[e];
  }
}

__global__ void k_inv_scatter(const int* __restrict__ unpool, int* __restrict__ inv, int npool){
  int i = blockIdx.x * blockDim.x + threadIdx.x;
  if (i < npool) inv[unpool[i]] = i;
}

// ---------- GEMM: C[n,128] = A[n,128] @ W[128,128] ----------
// 64 rows x 128 cols per block; 256 threads; 4x8 register tile per thread.
__global__ __launch_bounds__(256) void k_gemm(const float* __restrict__ A,
                                              const float* __restrict__ W,
                                              float* __restrict__ C, int n){
  __shared__ float As[16][68];
  __shared__ float Ws[16][128];
  const int t    = threadIdx.x;
  const int row0 = blockIdx.x * 64;
  const int tc   = t & 15;
  const int tr   = t >> 4;
  const int sr   = t >> 2;
  const int sk   = (t & 3) * 4;

  float acc[4][8];
  #pragma unroll
  for (int i = 0; i < 4; i++)
    #pragma unroll
    for (int j = 0; j < 8; j++) acc[i][j] = 0.f;

  for (int kt = 0; kt < 128; kt += 16){
    float4 av = make_float4(0.f, 0.f, 0.f, 0.f);
    int arow = row0 + sr;
    if (arow < n) av = *(const float4*)(A + (long)arow * DD + kt + sk);
    const float4 wv0 = *(const float4*)(W + (long)(kt + tr) * DD + tc * 8);
    const float4 wv1 = *(const float4*)(W + (long)(kt + tr) * DD + tc * 8 + 4);
    __syncthreads();
    As[sk + 0][sr] = av.x;
    As[sk + 1][sr] = av.y;
    As[sk + 2][sr] = av.z;
    As[sk + 3][sr] = av.w;
    *(float4*)(&Ws[tr][tc * 8])     = wv0;
    *(float4*)(&Ws[tr][tc * 8 + 4]) = wv1;
    __syncthreads();
    #pragma unroll
    for (int k = 0; k < 16; k++){
      const float4 a4 = *(const float4*)(&As[k][tr * 4]);
      const float4 w0 = *(const float4*)(&Ws[k][tc * 8]);
      const float4 w1 = *(const float4*)(&Ws[k][tc * 8 + 4]);
      const float ar[4] = {a4.x, a4.y, a4.z, a4.w};
      const float wr[8] = {w0.x, w0.y, w0.z, w0.w, w1.x, w1.y, w1.z, w1.w};
      #pragma unroll
      for (int i = 0; i < 4; i++)
        #pragma unroll
        for (int j = 0; j < 8; j++)
          acc[i][j] += ar[i] * wr[j];
    }
  }
  #pragma unroll
  for (int i = 0; i < 4; i++){
    int row = row0 + tr * 4 + i;
    if (row < n){
      *(float4*)(C + (long)row * DD + tc * 8)     = make_float4(acc[i][0], acc[i][1], acc[i][2], acc[i][3]);
      *(float4*)(C + (long)row * DD + tc * 8 + 4) = make_float4(acc[i][4], acc[i][5], acc[i][6], acc[i][7]);
    }
  }
}

// ---------- fused CSR aggregation + self-loop + bias + ELU ----------
__global__ __launch_bounds__(256) void k_agg_csr(const float* __restrict__ xw,
    const int* __restrict__ rptr, const int* __restrict__ csrc,
    const float* __restrict__ dinv, const float* __restrict__ b,
    float* __restrict__ out, int n){
  int row = blockIdx.x * 4 + (threadIdx.x >> 6);
  if (row >= n) return;
  int c = (threadIdx.x & 63) * 2;
  float ax = 0.f, ay = 0.f, bx = 0.f, by = 0.f;
  int j0 = rptr[row], j1 = rptr[row + 1];
  int j = j0;
  for (; j + 1 < j1; j += 2){
    int s0 = csrc[j], s1 = csrc[j + 1];
    float w0 = dinv[s0], w1 = dinv[s1];
    float2 v0 = *(const float2*)(xw + (long)s0 * DD + c);
    float2 v1 = *(const float2*)(xw + (long)s1 * DD + c);
    ax += v0.x * w0; ay += v0.y * w0;
    bx += v1.x * w1; by += v1.y * w1;
  }
  if (j < j1){
    int s0 = csrc[j];
    float w0 = dinv[s0];
    float2 v0 = *(const float2*)(xw + (long)s0 * DD + c);
    ax += v0.x * w0; ay += v0.y * w0;
  }
  ax += bx; ay += by;
  float dd = dinv[row];
  float2 sv = *(const float2*)(xw + (long)row * DD + c);
  float2 bb = *(const float2*)(b + c);
  float vx = ax * dd + sv.x * dd * dd + bb.x;
  float vy = ay * dd + sv.y * dd * dd + bb.y;
  vx = vx > 0.f ? vx : expm1f(vx);
  vy = vy > 0.f ? vy : expm1f(vy);
  *(float2*)(out + (long)row * DD + c) = make_float2(vx, vy);
}

__global__ __launch_bounds__(256) void k_agg_csr_sp(const float* __restrict__ hw,
    const int* __restrict__ inv, const int* __restrict__ rptr, const int* __restrict__ csrc,
    const float* __restrict__ dinv, const float* __restrict__ b,
    float* __restrict__ out, int n){
  int row = blockIdx.x * 4 + (threadIdx.x >> 6);
  if (row >= n) return;
  int c = (threadIdx.x & 63) * 2;
  float ax = 0.f, ay = 0.f;
  int j0 = rptr[row], j1 = rptr[row + 1];
  for (int j = j0; j < j1; j++){
    int s = csrc[j];
    int p = inv[s];
    if (p >= 0){
      float w = dinv[s];
      float2 v = *(const float2*)(hw + (long)p * DD + c);
      ax += v.x * w; ay += v.y * w;
    }
  }
  float dd = dinv[row];
  int pr = inv[row];
  float sx = 0.f, sy = 0.f;
  if (pr >= 0){
    float2 sv = *(const float2*)(hw + (long)pr * DD + c);
    sx = sv.x; sy = sv.y;
  }
  float2 bb = *(const float2*)(b + c);
  float vx = ax * dd + sx * dd * dd + bb.x;
  float vy = ay * dd + sy * dd * dd + bb.y;
  vx = vx > 0.f ? vx : expm1f(vx);
  vy = vy > 0.f ? vy : expm1f(vy);
  *(float2*)(out + (long)row * DD + c) = make_float2(vx, vy);
}

extern "C" void kernel_launch(void* const* d_in, const int* in_sizes, int n_in,
                              void* d_out, int out_size, void* d_ws, size_t ws_size,
                              hipStream_t stream) {
  const int*   edge   = (const int*)d_in[1];
  const float* px     = (const float*)d_in[2];
  const int*   pedge  = (const int*)d_in[3];
  const int*   unpool = (const int*)d_in[4];
  const float* W0 = (const float*)d_in[5]; const float* b0 = (const float*)d_in[6];
  const float* W1 = (const float*)d_in[7]; const float* b1 = (const float*)d_in[8];
  const float* W2 = (const float*)d_in[9]; const float* b2 = (const float*)d_in[10];
  const int n_full = in_sizes[0] / DD;
  const int E_full = in_sizes[1] / 2;
  const int n_pool = in_sizes[2] / DD;
  const int E_pool = in_sizes[3] / 2;
  float* out = (float*)d_out;

  // ---- workspace layout ----
  char* w = (char*)d_ws;
  size_t off = 0;
  auto alloc = [&](size_t bytes) -> void* {
    void* p = (void*)(w + off);
    off += (bytes + 255) / 256 * 256;
    return p;
  };
  float* dinv_p = (float*)alloc((size_t)n_pool * 4);
  float* dinv_f = (float*)alloc((size_t)n_full * 4);
  int* cnt_p  = (int*)alloc((size_t)n_pool * 4);
  int* cnt_f  = (int*)alloc((size_t)n_full * 4);
  int* rptr_p = (int*)alloc((size_t)(n_pool + 1) * 4);
  int* rptr_f = (int*)alloc((size_t)(n_full + 1) * 4);
  int* csrc_p = (int*)alloc((size_t)E_pool * 4);
  int* csrc_f = (int*)alloc((size_t)E_full * 4);
  int* invm   = (int*)alloc((size_t)n_full * 4);
  const int nbf = cdiv(n_full, 1024), nbp = cdiv(n_pool, 1024);
  int* bsum_f = (int*)alloc((size_t)nbf * 4);
  int* bsum_p = (int*)alloc((size_t)nbp * 4);
  const size_t big = (size_t)n_full * DD * 4;
  float* bufA = (float*)alloc(big);
  float* bufB = (float*)alloc(big);

  const int* src_f = edge;          const int* dst_f = edge + E_full;
  const int* src_p = pedge;         const int* dst_p = pedge + E_pool;

  // ---- CSR build (both graphs) + inverse unpool map ----
  hipMemsetAsync(cnt_p, 0, (size_t)n_pool * 4, stream);
  hipMemsetAsync(cnt_f, 0, (size_t)n_full * 4, stream);
  hipMemsetAsync(invm, 0xFF, (size_t)n_full * 4, stream);   // -1
  k_count<<<cdiv(E_pool,256),256,0,stream>>>(dst_p, cnt_p, E_pool);
  k_count<<<cdiv(E_full,256),256,0,stream>>>(dst_f, cnt_f, E_full);
  k_bsum<<<nbf + nbp,256,0,stream>>>(cnt_f, n_full, cnt_p, n_pool, bsum_f, bsum_p, nbf);
  k_scan_b<<<1,128,0,stream>>>(bsum_f, nbf, bsum_p, nbp);
  // reuse cnt arrays as cursors (written by k_scan_f)
  k_scan_f<<<nbf + nbp,256,0,stream>>>(cnt_f, n_full, bsum_f, cnt_p, n_pool, bsum_p,
                                       rptr_f, cnt_f, dinv_f, rptr_p, cnt_p, dinv_p,
                                       nbf, E_full, E_pool);
  k_fill<<<cdiv(E_pool,256),256,0,stream>>>(src_p, dst_p, cnt_p, csrc_p, E_pool);
  k_fill<<<cdiv(E_full,256),256,0,stream>>>(src_f, dst_f, cnt_f, csrc_f, E_full);
  k_inv_scatter<<<cdiv(n_pool,256),256,0,stream>>>(unpool, invm, n_pool);

  float* xw0 = bufA;   // pool rows
  float* h0  = bufB;   // pool rows
  float* hw1 = bufA;   // pool rows (xw0 dead)
  float* y1  = bufB;   // full rows (h0 dead after gemm)
  float* xw2 = bufA;   // full rows (hw1 dead)

  // conv0 (pooled graph), fused agg+bias+ELU
  k_gemm<<<cdiv(n_pool,64),256,0,stream>>>(px, W0, xw0, n_pool);
  k_agg_csr<<<cdiv(n_pool,4),256,0,stream>>>(xw0, rptr_p, csrc_p, dinv_p, b0, h0, n_pool);

  // conv1 (full graph, sparse input via inverse map)
  k_gemm<<<cdiv(n_pool,64),256,0,stream>>>(h0, W1, hw1, n_pool);
  k_agg_csr_sp<<<cdiv(n_full,4),256,0,stream>>>(hw1, invm, rptr_f, csrc_f, dinv_f, b1, y1, n_full);

  // conv2 (full graph, dense)
  k_gemm<<<cdiv(n_full,64),256,0,stream>>>(y1, W2, xw2, n_full);
  k_agg_csr<<<cdiv(n_full,4),256,0,stream>>>(xw2, rptr_f, csrc_f, dinv_f, b2, out, n_full);
}

// Round 5
// 329.232 us; speedup vs baseline: 8.2543x; 1.1881x over previous
//
#include <hip/hip_runtime.h>
#include <math.h>

#define DD 128

static inline int cdiv(long a, long b){ return (int)((a + b - 1) / b); }

// ---------- degree count (both graphs, one launch) ----------
__global__ void k_count2(const int* __restrict__ dst_f, int Ef, int* __restrict__ cnt_f,
                         const int* __restrict__ dst_p, int Ep, int* __restrict__ cnt_p){
  int e = blockIdx.x * blockDim.x + threadIdx.x;
  if (e < Ef) atomicAdd(&cnt_f[dst_f[e]], 1);
  else { e -= Ef; if (e < Ep) atomicAdd(&cnt_p[dst_p[e]], 1); }
}

// ---------- hierarchical scan phase 1 + inv scatter (fused) ----------
__global__ __launch_bounds__(256) void k_bsum(
    const int* __restrict__ cnt_f, int nf, const int* __restrict__ cnt_p, int np,
    int* __restrict__ bsum_f, int* __restrict__ bsum_p, int nbf, int nbp,
    const int* __restrict__ unpool, int* __restrict__ inv, int npool){
  int bi = blockIdx.x;
  if (bi >= nbf + nbp){           // trailing blocks: inverse unpool map
    int i = (bi - nbf - nbp) * 256 + threadIdx.x;
    if (i < npool) inv[unpool[i]] = i;
    return;
  }
  const int* cnt; int n; int* bsum; int b;
  if (bi < nbf){ cnt = cnt_f; n = nf; bsum = bsum_f; b = bi; }
  else         { cnt = cnt_p; n = np; bsum = bsum_p; b = bi - nbf; }
  __shared__ int s[256];
  int t = threadIdx.x;
  long base = (long)b * 1024 + t * 4;
  int v = 0;
  if (base + 3 < n){ int4 q = *(const int4*)(cnt + base); v = q.x + q.y + q.z + q.w; }
  else { for (int j = 0; j < 4; j++) if (base + j < n) v += cnt[base + j]; }
  s[t] = v; __syncthreads();
  for (int off = 128; off > 0; off >>= 1){ if (t < off) s[t] += s[t + off]; __syncthreads(); }
  if (t == 0) bsum[b] = s[0];
}

// phase 2: exclusive scan of block sums
__global__ __launch_bounds__(128) void k_scan_b(int* __restrict__ bsum_f, int nbf,
                                                int* __restrict__ bsum_p, int nbp){
  __shared__ int s[128];
  int t = threadIdx.x;
  int v = (t < nbf) ? bsum_f[t] : 0;
  s[t] = v; __syncthreads();
  for (int off = 1; off < 128; off <<= 1){ int u = (t >= off) ? s[t - off] : 0; __syncthreads(); s[t] += u; __syncthreads(); }
  if (t < nbf) bsum_f[t] = s[t] - v;
  __syncthreads();
  int v2 = (t < nbp) ? bsum_p[t] : 0;
  s[t] = v2; __syncthreads();
  for (int off = 1; off < 128; off <<= 1){ int u = (t >= off) ? s[t - off] : 0; __syncthreads(); s[t] += u; __syncthreads(); }
  if (t < nbp) bsum_p[t] = s[t] - v2;
}

// phase 3: local scan -> rptr, cursor copy, dinv
__global__ __launch_bounds__(256) void k_scan_f(
    const int* __restrict__ cnt_f, int nf, const int* __restrict__ bsum_f,
    const int* __restrict__ cnt_p, int np, const int* __restrict__ bsum_p,
    int* __restrict__ rptr_f, int* __restrict__ cur_f, float* __restrict__ dinv_f,
    int* __restrict__ rptr_p, int* __restrict__ cur_p, float* __restrict__ dinv_p,
    int nbf, int Ef, int Ep){
  const int* cnt; const int* bsum; int* rptr; int* cur; float* dinv; int n; int b;
  if ((int)blockIdx.x < nbf){ cnt=cnt_f; bsum=bsum_f; rptr=rptr_f; cur=cur_f; dinv=dinv_f; n=nf; b=blockIdx.x; }
  else                      { cnt=cnt_p; bsum=bsum_p; rptr=rptr_p; cur=cur_p; dinv=dinv_p; n=np; b=blockIdx.x-nbf; }
  __shared__ int s[256];
  int t = threadIdx.x;
  long base = (long)b * 1024 + t * 4;
  int c0=0,c1=0,c2=0,c3=0;
  if (base + 3 < n){ int4 q = *(const int4*)(cnt + base); c0=q.x; c1=q.y; c2=q.z; c3=q.w; }
  else {
    if (base + 0 < n) c0 = cnt[base + 0];
    if (base + 1 < n) c1 = cnt[base + 1];
    if (base + 2 < n) c2 = cnt[base + 2];
  }
  int tsum = c0 + c1 + c2 + c3;
  s[t] = tsum; __syncthreads();
  for (int off = 1; off < 256; off <<= 1){ int u = (t >= off) ? s[t - off] : 0; __syncthreads(); s[t] += u; __syncthreads(); }
  int run = bsum[b] + s[t] - tsum;
  int r0 = run, r1 = r0 + c0, r2 = r1 + c1, r3 = r2 + c2;
  if (base + 3 < n){
    *(int4*)(rptr + base) = make_int4(r0, r1, r2, r3);
    *(int4*)(cur + base)  = make_int4(r0, r1, r2, r3);
    dinv[base + 0] = rsqrtf((float)(c0 + 1));
    dinv[base + 1] = rsqrtf((float)(c1 + 1));
    dinv[base + 2] = rsqrtf((float)(c2 + 1));
    dinv[base + 3] = rsqrtf((float)(c3 + 1));
  } else {
    if (base + 0 < n){ rptr[base+0]=r0; cur[base+0]=r0; dinv[base+0]=rsqrtf((float)(c0+1)); }
    if (base + 1 < n){ rptr[base+1]=r1; cur[base+1]=r1; dinv[base+1]=rsqrtf((float)(c1+1)); }
    if (base + 2 < n){ rptr[base+2]=r2; cur[base+2]=r2; dinv[base+2]=rsqrtf((float)(c2+1)); }
  }
  if (blockIdx.x == 0 && t == 0){ rptr_f[nf] = Ef; rptr_p[np] = Ep; }
}

// ---------- CSR fill (both graphs) + weight/translation precompute ----------
__global__ void k_fill2(const int* __restrict__ src_f, const int* __restrict__ dst_f, int Ef,
                        int* __restrict__ cur_f, int* __restrict__ csrc_f,
                        float* __restrict__ wsrc_f, int* __restrict__ csrc1_f,
                        const float* __restrict__ dinv_f, const int* __restrict__ inv,
                        const int* __restrict__ src_p, const int* __restrict__ dst_p, int Ep,
                        int* __restrict__ cur_p, int* __restrict__ csrc_p,
                        float* __restrict__ wsrc_p, const float* __restrict__ dinv_p){
  int e = blockIdx.x * blockDim.x + threadIdx.x;
  if (e < Ef){
    int s = src_f[e];
    int p = atomicAdd(&cur_f[dst_f[e]], 1);
    csrc_f[p]  = s;
    wsrc_f[p]  = dinv_f[s];
    csrc1_f[p] = inv[s];
  } else {
    e -= Ef;
    if (e < Ep){
      int s = src_p[e];
      int p = atomicAdd(&cur_p[dst_p[e]], 1);
      csrc_p[p] = s;
      wsrc_p[p] = dinv_p[s];
    }
  }
}

// ---------- GEMM: C[n,128] = A[n,128] @ W[128,128] ----------
__global__ __launch_bounds__(256) void k_gemm(const float* __restrict__ A,
                                              const float* __restrict__ W,
                                              float* __restrict__ C, int n){
  __shared__ float As[16][68];
  __shared__ float Ws[16][128];
  const int t    = threadIdx.x;
  const int row0 = blockIdx.x * 64;
  const int tc   = t & 15;
  const int tr   = t >> 4;
  const int sr   = t >> 2;
  const int sk   = (t & 3) * 4;

  float acc[4][8];
  #pragma unroll
  for (int i = 0; i < 4; i++)
    #pragma unroll
    for (int j = 0; j < 8; j++) acc[i][j] = 0.f;

  for (int kt = 0; kt < 128; kt += 16){
    float4 av = make_float4(0.f, 0.f, 0.f, 0.f);
    int arow = row0 + sr;
    if (arow < n) av = *(const float4*)(A + (long)arow * DD + kt + sk);
    const float4 wv0 = *(const float4*)(W + (long)(kt + tr) * DD + tc * 8);
    const float4 wv1 = *(const float4*)(W + (long)(kt + tr) * DD + tc * 8 + 4);
    __syncthreads();
    As[sk + 0][sr] = av.x;
    As[sk + 1][sr] = av.y;
    As[sk + 2][sr] = av.z;
    As[sk + 3][sr] = av.w;
    *(float4*)(&Ws[tr][tc * 8])     = wv0;
    *(float4*)(&Ws[tr][tc * 8 + 4]) = wv1;
    __syncthreads();
    #pragma unroll
    for (int k = 0; k < 16; k++){
      const float4 a4 = *(const float4*)(&As[k][tr * 4]);
      const float4 w0 = *(const float4*)(&Ws[k][tc * 8]);
      const float4 w1 = *(const float4*)(&Ws[k][tc * 8 + 4]);
      const float ar[4] = {a4.x, a4.y, a4.z, a4.w};
      const float wr[8] = {w0.x, w0.y, w0.z, w0.w, w1.x, w1.y, w1.z, w1.w};
      #pragma unroll
      for (int i = 0; i < 4; i++)
        #pragma unroll
        for (int j = 0; j < 8; j++)
          acc[i][j] += ar[i] * wr[j];
    }
  }
  #pragma unroll
  for (int i = 0; i < 4; i++){
    int row = row0 + tr * 4 + i;
    if (row < n){
      *(float4*)(C + (long)row * DD + tc * 8)     = make_float4(acc[i][0], acc[i][1], acc[i][2], acc[i][3]);
      *(float4*)(C + (long)row * DD + tc * 8 + 4) = make_float4(acc[i][4], acc[i][5], acc[i][6], acc[i][7]);
    }
  }
}

// ---------- fused CSR aggregation + self-loop + bias + ELU ----------
// one wave per dst row; wave-uniform scalar index/weight loads; 4 gathers in flight
__global__ __launch_bounds__(256) void k_agg_csr(const float* __restrict__ xw,
    const int* __restrict__ rptr, const int* __restrict__ csrc, const float* __restrict__ wsrc,
    const float* __restrict__ dinv, const float* __restrict__ b,
    float* __restrict__ out, int n){
  int row = blockIdx.x * 4 + (threadIdx.x >> 6);
  if (row >= n) return;
  int c = (threadIdx.x & 63) * 2;
  int j0 = __builtin_amdgcn_readfirstlane(rptr[row]);
  int j1 = __builtin_amdgcn_readfirstlane(rptr[row + 1]);
  float ax0=0.f, ay0=0.f, ax1=0.f, ay1=0.f, ax2=0.f, ay2=0.f, ax3=0.f, ay3=0.f;
  int j = j0;
  for (; j + 3 < j1; j += 4){
    int s0 = csrc[j],   s1 = csrc[j+1], s2 = csrc[j+2], s3 = csrc[j+3];
    float w0 = wsrc[j], w1 = wsrc[j+1], w2 = wsrc[j+2], w3 = wsrc[j+3];
    float2 v0 = *(const float2*)(xw + (long)s0 * DD + c);
    float2 v1 = *(const float2*)(xw + (long)s1 * DD + c);
    float2 v2 = *(const float2*)(xw + (long)s2 * DD + c);
    float2 v3 = *(const float2*)(xw + (long)s3 * DD + c);
    ax0 += v0.x * w0; ay0 += v0.y * w0;
    ax1 += v1.x * w1; ay1 += v1.y * w1;
    ax2 += v2.x * w2; ay2 += v2.y * w2;
    ax3 += v3.x * w3; ay3 += v3.y * w3;
  }
  for (; j < j1; j++){
    int s0 = csrc[j]; float w0 = wsrc[j];
    float2 v0 = *(const float2*)(xw + (long)s0 * DD + c);
    ax0 += v0.x * w0; ay0 += v0.y * w0;
  }
  float ax = (ax0 + ax1) + (ax2 + ax3);
  float ay = (ay0 + ay1) + (ay2 + ay3);
  float dd = dinv[row];
  float2 sv = *(const float2*)(xw + (long)row * DD + c);
  float2 bb = *(const float2*)(b + c);
  float vx = ax * dd + sv.x * dd * dd + bb.x;
  float vy = ay * dd + sv.y * dd * dd + bb.y;
  vx = vx > 0.f ? vx : expm1f(vx);
  vy = vy > 0.f ? vy : expm1f(vy);
  *(float2*)(out + (long)row * DD + c) = make_float2(vx, vy);
}

// sparse-input variant: pre-translated indices csrc1 (pool row or -1), weights wsrc
__global__ __launch_bounds__(256) void k_agg_csr_sp(const float* __restrict__ hw,
    const int* __restrict__ inv, const int* __restrict__ rptr,
    const int* __restrict__ csrc1, const float* __restrict__ wsrc,
    const float* __restrict__ dinv, const float* __restrict__ b,
    float* __restrict__ out, int n){
  int row = blockIdx.x * 4 + (threadIdx.x >> 6);
  if (row >= n) return;
  int c = (threadIdx.x & 63) * 2;
  int j0 = __builtin_amdgcn_readfirstlane(rptr[row]);
  int j1 = __builtin_amdgcn_readfirstlane(rptr[row + 1]);
  float ax0=0.f, ay0=0.f, ax1=0.f, ay1=0.f;
  int j = j0;
  for (; j + 1 < j1; j += 2){
    int p0 = csrc1[j], p1 = csrc1[j+1];
    float w0 = wsrc[j], w1 = wsrc[j+1];
    if (p0 >= 0){
      float2 v = *(const float2*)(hw + (long)p0 * DD + c);
      ax0 += v.x * w0; ay0 += v.y * w0;
    }
    if (p1 >= 0){
      float2 v = *(const float2*)(hw + (long)p1 * DD + c);
      ax1 += v.x * w1; ay1 += v.y * w1;
    }
  }
  if (j < j1){
    int p0 = csrc1[j]; float w0 = wsrc[j];
    if (p0 >= 0){
      float2 v = *(const float2*)(hw + (long)p0 * DD + c);
      ax0 += v.x * w0; ay0 += v.y * w0;
    }
  }
  float ax = ax0 + ax1, ay = ay0 + ay1;
  float dd = dinv[row];
  int pr = inv[row];
  float sx = 0.f, sy = 0.f;
  if (pr >= 0){
    float2 sv = *(const float2*)(hw + (long)pr * DD + c);
    sx = sv.x; sy = sv.y;
  }
  float2 bb = *(const float2*)(b + c);
  float vx = ax * dd + sx * dd * dd + bb.x;
  float vy = ay * dd + sy * dd * dd + bb.y;
  vx = vx > 0.f ? vx : expm1f(vx);
  vy = vy > 0.f ? vy : expm1f(vy);
  *(float2*)(out + (long)row * DD + c) = make_float2(vx, vy);
}

extern "C" void kernel_launch(void* const* d_in, const int* in_sizes, int n_in,
                              void* d_out, int out_size, void* d_ws, size_t ws_size,
                              hipStream_t stream) {
  const int*   edge   = (const int*)d_in[1];
  const float* px     = (const float*)d_in[2];
  const int*   pedge  = (const int*)d_in[3];
  const int*   unpool = (const int*)d_in[4];
  const float* W0 = (const float*)d_in[5]; const float* b0 = (const float*)d_in[6];
  const float* W1 = (const float*)d_in[7]; const float* b1 = (const float*)d_in[8];
  const float* W2 = (const float*)d_in[9]; const float* b2 = (const float*)d_in[10];
  const int n_full = in_sizes[0] / DD;
  const int E_full = in_sizes[1] / 2;
  const int n_pool = in_sizes[2] / DD;
  const int E_pool = in_sizes[3] / 2;
  float* out = (float*)d_out;

  // ---- workspace layout ----
  char* w = (char*)d_ws;
  size_t off = 0;
  auto alloc = [&](size_t bytes) -> void* {
    void* p = (void*)(w + off);
    off += (bytes + 255) / 256 * 256;
    return p;
  };
  float* dinv_p = (float*)alloc((size_t)n_pool * 4);
  float* dinv_f = (float*)alloc((size_t)n_full * 4);
  int* cnt_p  = (int*)alloc((size_t)n_pool * 4);
  int* cnt_f  = (int*)alloc((size_t)n_full * 4);
  int* rptr_p = (int*)alloc((size_t)(n_pool + 1) * 4);
  int* rptr_f = (int*)alloc((size_t)(n_full + 1) * 4);
  int* csrc_p = (int*)alloc((size_t)E_pool * 4);
  int* csrc_f = (int*)alloc((size_t)E_full * 4);
  float* wsrc_p = (float*)alloc((size_t)E_pool * 4);
  float* wsrc_f = (float*)alloc((size_t)E_full * 4);
  int* csrc1_f  = (int*)alloc((size_t)E_full * 4);
  int* invm   = (int*)alloc((size_t)n_full * 4);
  const int nbf = cdiv(n_full, 1024), nbp = cdiv(n_pool, 1024);
  int* bsum_f = (int*)alloc((size_t)nbf * 4);
  int* bsum_p = (int*)alloc((size_t)nbp * 4);
  const size_t big = (size_t)n_full * DD * 4;
  float* bufA = (float*)alloc(big);
  float* bufB = (float*)alloc(big);

  const int* src_f = edge;          const int* dst_f = edge + E_full;
  const int* src_p = pedge;         const int* dst_p = pedge + E_pool;

  // ---- CSR build (both graphs) + inverse unpool map ----
  hipMemsetAsync(cnt_p, 0, (size_t)n_pool * 4, stream);
  hipMemsetAsync(cnt_f, 0, (size_t)n_full * 4, stream);
  hipMemsetAsync(invm, 0xFF, (size_t)n_full * 4, stream);   // -1
  k_count2<<<cdiv((long)E_full + E_pool,256),256,0,stream>>>(dst_f, E_full, cnt_f, dst_p, E_pool, cnt_p);
  const int nbi = cdiv(n_pool, 256);
  k_bsum<<<nbf + nbp + nbi,256,0,stream>>>(cnt_f, n_full, cnt_p, n_pool, bsum_f, bsum_p,
                                           nbf, nbp, unpool, invm, n_pool);
  k_scan_b<<<1,128,0,stream>>>(bsum_f, nbf, bsum_p, nbp);
  k_scan_f<<<nbf + nbp,256,0,stream>>>(cnt_f, n_full, bsum_f, cnt_p, n_pool, bsum_p,
                                       rptr_f, cnt_f, dinv_f, rptr_p, cnt_p, dinv_p,
                                       nbf, E_full, E_pool);
  k_fill2<<<cdiv((long)E_full + E_pool,256),256,0,stream>>>(
      src_f, dst_f, E_full, cnt_f, csrc_f, wsrc_f, csrc1_f, dinv_f, invm,
      src_p, dst_p, E_pool, cnt_p, csrc_p, wsrc_p, dinv_p);

  float* xw0 = bufA;   // pool rows
  float* h0  = bufB;   // pool rows
  float* hw1 = bufA;   // pool rows (xw0 dead)
  float* y1  = bufB;   // full rows (h0 dead after gemm)
  float* xw2 = bufA;   // full rows (hw1 dead)

  // conv0 (pooled graph), fused agg+bias+ELU
  k_gemm<<<cdiv(n_pool,64),256,0,stream>>>(px, W0, xw0, n_pool);
  k_agg_csr<<<cdiv(n_pool,4),256,0,stream>>>(xw0, rptr_p, csrc_p, wsrc_p, dinv_p, b0, h0, n_pool);

  // conv1 (full graph, sparse input via pre-translated indices)
  k_gemm<<<cdiv(n_pool,64),256,0,stream>>>(h0, W1, hw1, n_pool);
  k_agg_csr_sp<<<cdiv(n_full,4),256,0,stream>>>(hw1, invm, rptr_f, csrc1_f, wsrc_f, dinv_f, b1, y1, n_full);

  // conv2 (full graph, dense)
  k_gemm<<<cdiv(n_full,64),256,0,stream>>>(y1, W2, xw2, n_full);
  k_agg_csr<<<cdiv(n_full,4),256,0,stream>>>(xw2, rptr_f, csrc_f, wsrc_f, dinv_f, b2, out, n_full);
}

// Round 6
// 311.218 us; speedup vs baseline: 8.7321x; 1.0579x over previous
//
#include <hip/hip_runtime.h>
#include <math.h>

#define DD 128

static inline int cdiv(long a, long b){ return (int)((a + b - 1) / b); }

__device__ __forceinline__ unsigned bfpack(float a, float b){
  unsigned ua = __float_as_uint(a), ub = __float_as_uint(b);
  ua = (ua + 0x7fffu + ((ua >> 16) & 1u)) >> 16;
  ub = (ub + 0x7fffu + ((ub >> 16) & 1u)) >> 16;
  return ua | (ub << 16);
}

// ---------- degree count (both graphs, one launch) ----------
__global__ void k_count2(const int* __restrict__ dst_f, int Ef, int* __restrict__ cnt_f,
                         const int* __restrict__ dst_p, int Ep, int* __restrict__ cnt_p){
  int e = blockIdx.x * blockDim.x + threadIdx.x;
  if (e < Ef) atomicAdd(&cnt_f[dst_f[e]], 1);
  else { e -= Ef; if (e < Ep) atomicAdd(&cnt_p[dst_p[e]], 1); }
}

// ---------- hierarchical scan phase 1 + inv scatter (fused) ----------
__global__ __launch_bounds__(256) void k_bsum(
    const int* __restrict__ cnt_f, int nf, const int* __restrict__ cnt_p, int np,
    int* __restrict__ bsum_f, int* __restrict__ bsum_p, int nbf, int nbp,
    const int* __restrict__ unpool, int* __restrict__ inv, int npool){
  int bi = blockIdx.x;
  if (bi >= nbf + nbp){
    int i = (bi - nbf - nbp) * 256 + threadIdx.x;
    if (i < npool) inv[unpool[i]] = i;
    return;
  }
  const int* cnt; int n; int* bsum; int b;
  if (bi < nbf){ cnt = cnt_f; n = nf; bsum = bsum_f; b = bi; }
  else         { cnt = cnt_p; n = np; bsum = bsum_p; b = bi - nbf; }
  __shared__ int s[256];
  int t = threadIdx.x;
  long base = (long)b * 1024 + t * 4;
  int v = 0;
  if (base + 3 < n){ int4 q = *(const int4*)(cnt + base); v = q.x + q.y + q.z + q.w; }
  else { for (int j = 0; j < 4; j++) if (base + j < n) v += cnt[base + j]; }
  s[t] = v; __syncthreads();
  for (int off = 128; off > 0; off >>= 1){ if (t < off) s[t] += s[t + off]; __syncthreads(); }
  if (t == 0) bsum[b] = s[0];
}

// phase 2: exclusive scan of block sums
__global__ __launch_bounds__(128) void k_scan_b(int* __restrict__ bsum_f, int nbf,
                                                int* __restrict__ bsum_p, int nbp){
  __shared__ int s[128];
  int t = threadIdx.x;
  int v = (t < nbf) ? bsum_f[t] : 0;
  s[t] = v; __syncthreads();
  for (int off = 1; off < 128; off <<= 1){ int u = (t >= off) ? s[t - off] : 0; __syncthreads(); s[t] += u; __syncthreads(); }
  if (t < nbf) bsum_f[t] = s[t] - v;
  __syncthreads();
  int v2 = (t < nbp) ? bsum_p[t] : 0;
  s[t] = v2; __syncthreads();
  for (int off = 1; off < 128; off <<= 1){ int u = (t >= off) ? s[t - off] : 0; __syncthreads(); s[t] += u; __syncthreads(); }
  if (t < nbp) bsum_p[t] = s[t] - v2;
}

// phase 3: local scan -> rptr, cursor copy, dinv
__global__ __launch_bounds__(256) void k_scan_f(
    const int* __restrict__ cnt_f, int nf, const int* __restrict__ bsum_f,
    const int* __restrict__ cnt_p, int np, const int* __restrict__ bsum_p,
    int* __restrict__ rptr_f, int* __restrict__ cur_f, float* __restrict__ dinv_f,
    int* __restrict__ rptr_p, int* __restrict__ cur_p, float* __restrict__ dinv_p,
    int nbf, int Ef, int Ep){
  const int* cnt; const int* bsum; int* rptr; int* cur; float* dinv; int n; int b;
  if ((int)blockIdx.x < nbf){ cnt=cnt_f; bsum=bsum_f; rptr=rptr_f; cur=cur_f; dinv=dinv_f; n=nf; b=blockIdx.x; }
  else                      { cnt=cnt_p; bsum=bsum_p; rptr=rptr_p; cur=cur_p; dinv=dinv_p; n=np; b=blockIdx.x-nbf; }
  __shared__ int s[256];
  int t = threadIdx.x;
  long base = (long)b * 1024 + t * 4;
  int c0=0,c1=0,c2=0,c3=0;
  if (base + 3 < n){ int4 q = *(const int4*)(cnt + base); c0=q.x; c1=q.y; c2=q.z; c3=q.w; }
  else {
    if (base + 0 < n) c0 = cnt[base + 0];
    if (base + 1 < n) c1 = cnt[base + 1];
    if (base + 2 < n) c2 = cnt[base + 2];
  }
  int tsum = c0 + c1 + c2 + c3;
  s[t] = tsum; __syncthreads();
  for (int off = 1; off < 256; off <<= 1){ int u = (t >= off) ? s[t - off] : 0; __syncthreads(); s[t] += u; __syncthreads(); }
  int run = bsum[b] + s[t] - tsum;
  int r0 = run, r1 = r0 + c0, r2 = r1 + c1, r3 = r2 + c2;
  if (base + 3 < n){
    *(int4*)(rptr + base) = make_int4(r0, r1, r2, r3);
    *(int4*)(cur + base)  = make_int4(r0, r1, r2, r3);
    dinv[base + 0] = rsqrtf((float)(c0 + 1));
    dinv[base + 1] = rsqrtf((float)(c1 + 1));
    dinv[base + 2] = rsqrtf((float)(c2 + 1));
    dinv[base + 3] = rsqrtf((float)(c3 + 1));
  } else {
    if (base + 0 < n){ rptr[base+0]=r0; cur[base+0]=r0; dinv[base+0]=rsqrtf((float)(c0+1)); }
    if (base + 1 < n){ rptr[base+1]=r1; cur[base+1]=r1; dinv[base+1]=rsqrtf((float)(c1+1)); }
    if (base + 2 < n){ rptr[base+2]=r2; cur[base+2]=r2; dinv[base+2]=rsqrtf((float)(c2+1)); }
  }
  if (blockIdx.x == 0 && t == 0){ rptr_f[nf] = Ef; rptr_p[np] = Ep; }
}

// ---------- CSR fill (both graphs) + weight/translation precompute ----------
__global__ void k_fill2(const int* __restrict__ src_f, const int* __restrict__ dst_f, int Ef,
                        int* __restrict__ cur_f, int* __restrict__ csrc_f,
                        float* __restrict__ wsrc_f, int* __restrict__ csrc1_f,
                        const float* __restrict__ dinv_f, const int* __restrict__ inv,
                        const int* __restrict__ src_p, const int* __restrict__ dst_p, int Ep,
                        int* __restrict__ cur_p, int* __restrict__ csrc_p,
                        float* __restrict__ wsrc_p, const float* __restrict__ dinv_p){
  int e = blockIdx.x * blockDim.x + threadIdx.x;
  if (e < Ef){
    int s = src_f[e];
    int p = atomicAdd(&cur_f[dst_f[e]], 1);
    csrc_f[p]  = s;
    wsrc_f[p]  = dinv_f[s];
    csrc1_f[p] = inv[s];
  } else {
    e -= Ef;
    if (e < Ep){
      int s = src_p[e];
      int p = atomicAdd(&cur_p[dst_p[e]], 1);
      csrc_p[p] = s;
      wsrc_p[p] = dinv_p[s];
    }
  }
}

// ---------- GEMM fp32 out ----------
__global__ __launch_bounds__(256) void k_gemm(const float* __restrict__ A,
                                              const float* __restrict__ W,
                                              float* __restrict__ C, int n){
  __shared__ float As[16][68];
  __shared__ float Ws[16][128];
  const int t    = threadIdx.x;
  const int row0 = blockIdx.x * 64;
  const int tc   = t & 15;
  const int tr   = t >> 4;
  const int sr   = t >> 2;
  const int sk   = (t & 3) * 4;

  float acc[4][8];
  #pragma unroll
  for (int i = 0; i < 4; i++)
    #pragma unroll
    for (int j = 0; j < 8; j++) acc[i][j] = 0.f;

  for (int kt = 0; kt < 128; kt += 16){
    float4 av = make_float4(0.f, 0.f, 0.f, 0.f);
    int arow = row0 + sr;
    if (arow < n) av = *(const float4*)(A + (long)arow * DD + kt + sk);
    const float4 wv0 = *(const float4*)(W + (long)(kt + tr) * DD + tc * 8);
    const float4 wv1 = *(const float4*)(W + (long)(kt + tr) * DD + tc * 8 + 4);
    __syncthreads();
    As[sk + 0][sr] = av.x;
    As[sk + 1][sr] = av.y;
    As[sk + 2][sr] = av.z;
    As[sk + 3][sr] = av.w;
    *(float4*)(&Ws[tr][tc * 8])     = wv0;
    *(float4*)(&Ws[tr][tc * 8 + 4]) = wv1;
    __syncthreads();
    #pragma unroll
    for (int k = 0; k < 16; k++){
      const float4 a4 = *(const float4*)(&As[k][tr * 4]);
      const float4 w0 = *(const float4*)(&Ws[k][tc * 8]);
      const float4 w1 = *(const float4*)(&Ws[k][tc * 8 + 4]);
      const float ar[4] = {a4.x, a4.y, a4.z, a4.w};
      const float wr[8] = {w0.x, w0.y, w0.z, w0.w, w1.x, w1.y, w1.z, w1.w};
      #pragma unroll
      for (int i = 0; i < 4; i++)
        #pragma unroll
        for (int j = 0; j < 8; j++)
          acc[i][j] += ar[i] * wr[j];
    }
  }
  #pragma unroll
  for (int i = 0; i < 4; i++){
    int row = row0 + tr * 4 + i;
    if (row < n){
      *(float4*)(C + (long)row * DD + tc * 8)     = make_float4(acc[i][0], acc[i][1], acc[i][2], acc[i][3]);
      *(float4*)(C + (long)row * DD + tc * 8 + 4) = make_float4(acc[i][4], acc[i][5], acc[i][6], acc[i][7]);
    }
  }
}

// ---------- GEMM bf16 out (for conv2 gather payload) ----------
__global__ __launch_bounds__(256) void k_gemm_b(const float* __restrict__ A,
                                                const float* __restrict__ W,
                                                unsigned short* __restrict__ C, int n){
  __shared__ float As[16][68];
  __shared__ float Ws[16][128];
  const int t    = threadIdx.x;
  const int row0 = blockIdx.x * 64;
  const int tc   = t & 15;
  const int tr   = t >> 4;
  const int sr   = t >> 2;
  const int sk   = (t & 3) * 4;

  float acc[4][8];
  #pragma unroll
  for (int i = 0; i < 4; i++)
    #pragma unroll
    for (int j = 0; j < 8; j++) acc[i][j] = 0.f;

  for (int kt = 0; kt < 128; kt += 16){
    float4 av = make_float4(0.f, 0.f, 0.f, 0.f);
    int arow = row0 + sr;
    if (arow < n) av = *(const float4*)(A + (long)arow * DD + kt + sk);
    const float4 wv0 = *(const float4*)(W + (long)(kt + tr) * DD + tc * 8);
    const float4 wv1 = *(const float4*)(W + (long)(kt + tr) * DD + tc * 8 + 4);
    __syncthreads();
    As[sk + 0][sr] = av.x;
    As[sk + 1][sr] = av.y;
    As[sk + 2][sr] = av.z;
    As[sk + 3][sr] = av.w;
    *(float4*)(&Ws[tr][tc * 8])     = wv0;
    *(float4*)(&Ws[tr][tc * 8 + 4]) = wv1;
    __syncthreads();
    #pragma unroll
    for (int k = 0; k < 16; k++){
      const float4 a4 = *(const float4*)(&As[k][tr * 4]);
      const float4 w0 = *(const float4*)(&Ws[k][tc * 8]);
      const float4 w1 = *(const float4*)(&Ws[k][tc * 8 + 4]);
      const float ar[4] = {a4.x, a4.y, a4.z, a4.w};
      const float wr[8] = {w0.x, w0.y, w0.z, w0.w, w1.x, w1.y, w1.z, w1.w};
      #pragma unroll
      for (int i = 0; i < 4; i++)
        #pragma unroll
        for (int j = 0; j < 8; j++)
          acc[i][j] += ar[i] * wr[j];
    }
  }
  #pragma unroll
  for (int i = 0; i < 4; i++){
    int row = row0 + tr * 4 + i;
    if (row < n){
      uint4 pk;
      pk.x = bfpack(acc[i][0], acc[i][1]);
      pk.y = bfpack(acc[i][2], acc[i][3]);
      pk.z = bfpack(acc[i][4], acc[i][5]);
      pk.w = bfpack(acc[i][6], acc[i][7]);
      *(uint4*)(C + (long)row * DD + tc * 8) = pk;
    }
  }
}

// ---------- fused CSR agg + self-loop + bias + ELU (fp32 payload) ----------
__global__ __launch_bounds__(256) void k_agg_csr(const float* __restrict__ xw,
    const int* __restrict__ rptr, const int* __restrict__ csrc, const float* __restrict__ wsrc,
    const float* __restrict__ dinv, const float* __restrict__ b,
    float* __restrict__ out, int n){
  int row = blockIdx.x * 4 + (threadIdx.x >> 6);
  if (row >= n) return;
  int c = (threadIdx.x & 63) * 2;
  int j0 = __builtin_amdgcn_readfirstlane(rptr[row]);
  int j1 = __builtin_amdgcn_readfirstlane(rptr[row + 1]);
  float ax0=0.f, ay0=0.f, ax1=0.f, ay1=0.f, ax2=0.f, ay2=0.f, ax3=0.f, ay3=0.f;
  int j = j0;
  for (; j + 3 < j1; j += 4){
    int s0 = csrc[j],   s1 = csrc[j+1], s2 = csrc[j+2], s3 = csrc[j+3];
    float w0 = wsrc[j], w1 = wsrc[j+1], w2 = wsrc[j+2], w3 = wsrc[j+3];
    float2 v0 = *(const float2*)(xw + (long)s0 * DD + c);
    float2 v1 = *(const float2*)(xw + (long)s1 * DD + c);
    float2 v2 = *(const float2*)(xw + (long)s2 * DD + c);
    float2 v3 = *(const float2*)(xw + (long)s3 * DD + c);
    ax0 += v0.x * w0; ay0 += v0.y * w0;
    ax1 += v1.x * w1; ay1 += v1.y * w1;
    ax2 += v2.x * w2; ay2 += v2.y * w2;
    ax3 += v3.x * w3; ay3 += v3.y * w3;
  }
  for (; j < j1; j++){
    int s0 = csrc[j]; float w0 = wsrc[j];
    float2 v0 = *(const float2*)(xw + (long)s0 * DD + c);
    ax0 += v0.x * w0; ay0 += v0.y * w0;
  }
  float ax = (ax0 + ax1) + (ax2 + ax3);
  float ay = (ay0 + ay1) + (ay2 + ay3);
  float dd = dinv[row];
  float2 sv = *(const float2*)(xw + (long)row * DD + c);
  float2 bb = *(const float2*)(b + c);
  float vx = ax * dd + sv.x * dd * dd + bb.x;
  float vy = ay * dd + sv.y * dd * dd + bb.y;
  vx = vx > 0.f ? vx : expm1f(vx);
  vy = vy > 0.f ? vy : expm1f(vy);
  *(float2*)(out + (long)row * DD + c) = make_float2(vx, vy);
}

// ---------- bf16-payload agg (conv2): unroll x8, fp32 accumulate/output ----------
__global__ __launch_bounds__(256) void k_agg_csr_b(const unsigned short* __restrict__ xwb,
    const int* __restrict__ rptr, const int* __restrict__ csrc, const float* __restrict__ wsrc,
    const float* __restrict__ dinv, const float* __restrict__ b,
    float* __restrict__ out, int n){
  int row = blockIdx.x * 4 + (threadIdx.x >> 6);
  if (row >= n) return;
  int c = (threadIdx.x & 63) * 2;
  int j0 = __builtin_amdgcn_readfirstlane(rptr[row]);
  int j1 = __builtin_amdgcn_readfirstlane(rptr[row + 1]);
  float ax[8], ay[8];
  #pragma unroll
  for (int i = 0; i < 8; i++){ ax[i] = 0.f; ay[i] = 0.f; }
  int j = j0;
  for (; j + 7 < j1; j += 8){
    #pragma unroll
    for (int i = 0; i < 8; i++){
      int s = csrc[j + i];
      float w = wsrc[j + i];
      unsigned v = *(const unsigned*)(xwb + (long)s * DD + c);
      ax[i] += __uint_as_float(v << 16) * w;
      ay[i] += __uint_as_float(v & 0xffff0000u) * w;
    }
  }
  for (; j < j1; j++){
    int s = csrc[j]; float w = wsrc[j];
    unsigned v = *(const unsigned*)(xwb + (long)s * DD + c);
    ax[0] += __uint_as_float(v << 16) * w;
    ay[0] += __uint_as_float(v & 0xffff0000u) * w;
  }
  float sax = ((ax[0]+ax[1])+(ax[2]+ax[3])) + ((ax[4]+ax[5])+(ax[6]+ax[7]));
  float say = ((ay[0]+ay[1])+(ay[2]+ay[3])) + ((ay[4]+ay[5])+(ay[6]+ay[7]));
  float dd = dinv[row];
  unsigned sv = *(const unsigned*)(xwb + (long)row * DD + c);
  float sx = __uint_as_float(sv << 16), sy = __uint_as_float(sv & 0xffff0000u);
  float2 bb = *(const float2*)(b + c);
  float vx = sax * dd + sx * dd * dd + bb.x;
  float vy = say * dd + sy * dd * dd + bb.y;
  vx = vx > 0.f ? vx : expm1f(vx);
  vy = vy > 0.f ? vy : expm1f(vy);
  *(float2*)(out + (long)row * DD + c) = make_float2(vx, vy);
}

// sparse-input variant (conv1): pre-translated indices, unroll x4
__global__ __launch_bounds__(256) void k_agg_csr_sp(const float* __restrict__ hw,
    const int* __restrict__ inv, const int* __restrict__ rptr,
    const int* __restrict__ csrc1, const float* __restrict__ wsrc,
    const float* __restrict__ dinv, const float* __restrict__ b,
    float* __restrict__ out, int n){
  int row = blockIdx.x * 4 + (threadIdx.x >> 6);
  if (row >= n) return;
  int c = (threadIdx.x & 63) * 2;
  int j0 = __builtin_amdgcn_readfirstlane(rptr[row]);
  int j1 = __builtin_amdgcn_readfirstlane(rptr[row + 1]);
  float ax[4], ay[4];
  #pragma unroll
  for (int i = 0; i < 4; i++){ ax[i] = 0.f; ay[i] = 0.f; }
  int j = j0;
  for (; j + 3 < j1; j += 4){
    #pragma unroll
    for (int i = 0; i < 4; i++){
      int p = csrc1[j + i];
      float w = wsrc[j + i];
      if (p >= 0){
        float2 v = *(const float2*)(hw + (long)p * DD + c);
        ax[i] += v.x * w; ay[i] += v.y * w;
      }
    }
  }
  for (; j < j1; j++){
    int p = csrc1[j]; float w = wsrc[j];
    if (p >= 0){
      float2 v = *(const float2*)(hw + (long)p * DD + c);
      ax[0] += v.x * w; ay[0] += v.y * w;
    }
  }
  float sax = (ax[0]+ax[1]) + (ax[2]+ax[3]);
  float say = (ay[0]+ay[1]) + (ay[2]+ay[3]);
  float dd = dinv[row];
  int pr = inv[row];
  float sx = 0.f, sy = 0.f;
  if (pr >= 0){
    float2 sv = *(const float2*)(hw + (long)pr * DD + c);
    sx = sv.x; sy = sv.y;
  }
  float2 bb = *(const float2*)(b + c);
  float vx = sax * dd + sx * dd * dd + bb.x;
  float vy = say * dd + sy * dd * dd + bb.y;
  vx = vx > 0.f ? vx : expm1f(vx);
  vy = vy > 0.f ? vy : expm1f(vy);
  *(float2*)(out + (long)row * DD + c) = make_float2(vx, vy);
}

extern "C" void kernel_launch(void* const* d_in, const int* in_sizes, int n_in,
                              void* d_out, int out_size, void* d_ws, size_t ws_size,
                              hipStream_t stream) {
  const int*   edge   = (const int*)d_in[1];
  const float* px     = (const float*)d_in[2];
  const int*   pedge  = (const int*)d_in[3];
  const int*   unpool = (const int*)d_in[4];
  const float* W0 = (const float*)d_in[5]; const float* b0 = (const float*)d_in[6];
  const float* W1 = (const float*)d_in[7]; const float* b1 = (const float*)d_in[8];
  const float* W2 = (const float*)d_in[9]; const float* b2 = (const float*)d_in[10];
  const int n_full = in_sizes[0] / DD;
  const int E_full = in_sizes[1] / 2;
  const int n_pool = in_sizes[2] / DD;
  const int E_pool = in_sizes[3] / 2;
  float* out = (float*)d_out;

  // ---- workspace layout ----
  char* w = (char*)d_ws;
  size_t off = 0;
  auto alloc = [&](size_t bytes) -> void* {
    void* p = (void*)(w + off);
    off += (bytes + 255) / 256 * 256;
    return p;
  };
  float* dinv_p = (float*)alloc((size_t)n_pool * 4);
  float* dinv_f = (float*)alloc((size_t)n_full * 4);
  // cnt_p and cnt_f contiguous -> single memset
  int* cnt_p  = (int*)alloc((size_t)n_pool * 4);
  int* cnt_f  = (int*)alloc((size_t)n_full * 4);
  size_t cnt_span = (size_t)((char*)(cnt_f + n_full) - (char*)cnt_p);
  int* rptr_p = (int*)alloc((size_t)(n_pool + 1) * 4);
  int* rptr_f = (int*)alloc((size_t)(n_full + 1) * 4);
  int* csrc_p = (int*)alloc((size_t)E_pool * 4);
  int* csrc_f = (int*)alloc((size_t)E_full * 4);
  float* wsrc_p = (float*)alloc((size_t)E_pool * 4);
  float* wsrc_f = (float*)alloc((size_t)E_full * 4);
  int* csrc1_f  = (int*)alloc((size_t)E_full * 4);
  int* invm   = (int*)alloc((size_t)n_full * 4);
  const int nbf = cdiv(n_full, 1024), nbp = cdiv(n_pool, 1024);
  int* bsum_f = (int*)alloc((size_t)nbf * 4);
  int* bsum_p = (int*)alloc((size_t)nbp * 4);
  const size_t big = (size_t)n_full * DD * 4;
  float* bufA = (float*)alloc(big);
  float* bufB = (float*)alloc(big);

  const int* src_f = edge;          const int* dst_f = edge + E_full;
  const int* src_p = pedge;         const int* dst_p = pedge + E_pool;

  // ---- CSR build (both graphs) + inverse unpool map ----
  hipMemsetAsync(cnt_p, 0, cnt_span, stream);
  hipMemsetAsync(invm, 0xFF, (size_t)n_full * 4, stream);   // -1
  k_count2<<<cdiv((long)E_full + E_pool,256),256,0,stream>>>(dst_f, E_full, cnt_f, dst_p, E_pool, cnt_p);
  const int nbi = cdiv(n_pool, 256);
  k_bsum<<<nbf + nbp + nbi,256,0,stream>>>(cnt_f, n_full, cnt_p, n_pool, bsum_f, bsum_p,
                                           nbf, nbp, unpool, invm, n_pool);
  k_scan_b<<<1,128,0,stream>>>(bsum_f, nbf, bsum_p, nbp);
  k_scan_f<<<nbf + nbp,256,0,stream>>>(cnt_f, n_full, bsum_f, cnt_p, n_pool, bsum_p,
                                       rptr_f, cnt_f, dinv_f, rptr_p, cnt_p, dinv_p,
                                       nbf, E_full, E_pool);
  k_fill2<<<cdiv((long)E_full + E_pool,256),256,0,stream>>>(
      src_f, dst_f, E_full, cnt_f, csrc_f, wsrc_f, csrc1_f, dinv_f, invm,
      src_p, dst_p, E_pool, cnt_p, csrc_p, wsrc_p, dinv_p);

  float* xw0 = bufA;                      // pool rows fp32
  float* h0  = bufB;                      // pool rows fp32
  float* hw1 = bufA;                      // pool rows fp32 (xw0 dead)
  float* y1  = bufB;                      // full rows fp32 (h0 dead after gemm)
  unsigned short* xw2b = (unsigned short*)bufA;  // full rows bf16 (hw1 dead)

  // conv0 (pooled graph)
  k_gemm<<<cdiv(n_pool,64),256,0,stream>>>(px, W0, xw0, n_pool);
  k_agg_csr<<<cdiv(n_pool,4),256,0,stream>>>(xw0, rptr_p, csrc_p, wsrc_p, dinv_p, b0, h0, n_pool);

  // conv1 (full graph, sparse input)
  k_gemm<<<cdiv(n_pool,64),256,0,stream>>>(h0, W1, hw1, n_pool);
  k_agg_csr_sp<<<cdiv(n_full,4),256,0,stream>>>(hw1, invm, rptr_f, csrc1_f, wsrc_f, dinv_f, b1, y1, n_full);

  // conv2 (full graph, bf16 gather payload)
  k_gemm_b<<<cdiv(n_full,64),256,0,stream>>>(y1, W2, xw2b, n_full);
  k_agg_csr_b<<<cdiv(n_full,4),256,0,stream>>>(xw2b, rptr_f, csrc_f, wsrc_f, dinv_f, b2, out, n_full);
}